// Round 12
// baseline (1202.355 us; speedup 1.0000x reference)
//
#include <hip/hip_runtime.h>
#include <hip/hip_bf16.h>

#define N_MOL 128
#define STRESS_FLOATS (N_MOL * 9)   // 1152
#define APB 400                     // atoms per bucket
#define MAXB 512                    // LDS sizing bound (B=500 <= MAXB)
#define EPB 2048                    // edges per scatter block
#define BLK 256

// ---------------------------------------------------------------------------
__global__ void zero_f32_kernel(float* __restrict__ p, size_t n) {
    size_t i = (size_t)blockIdx.x * blockDim.x + threadIdx.x;
    if (i < n) p[i] = 0.f;
}

// ---------------------------------------------------------------------------
// Pass C: histogram -> block prefix-scan -> reservation -> LDS bucket-major
// staging -> COALESCED stream-out (runs of consecutive slots per bucket).
// Also stress LDS accumulation -> spart row RMW (accumulated across chunks).
// ---------------------------------------------------------------------------
__global__ void __launch_bounds__(256)
scatter_kernel(const float* __restrict__ dEdRij,
               const float* __restrict__ Rij,
               const int*   __restrict__ idx_i,
               const int*   __restrict__ idx_j,
               const int*   __restrict__ idx_m,
               float4* __restrict__ rec,    // [B][CAP]
               int*    __restrict__ cnt,    // [B] (this chunk's slice)
               float*  __restrict__ spart,  // [rows][1152], RMW across chunks
               int e0_chunk, int n_edges_chunk, int B, int CAP)
{
    __shared__ int    hist[MAXB];      // per-bucket count
    __shared__ int    scan[MAXB];      // inclusive prefix
    __shared__ int    cur[MAXB];       // staging cursor (starts at exclusive)
    __shared__ int    shiftb[MAXB];    // rec-index shift per bucket
    __shared__ float  smem[STRESS_FLOATS];
    __shared__ float4 stg[EPB * 2];    // 64 KB bucket-major staging

    for (int t = threadIdx.x; t < MAXB; t += blockDim.x) hist[t] = 0;
    for (int t = threadIdx.x; t < STRESS_FLOATS; t += blockDim.x) smem[t] = 0.f;
    __syncthreads();

    const int be0 = e0_chunk + blockIdx.x * EPB;
    const int be1 = min(be0 + EPB, e0_chunk + n_edges_chunk);

    // ---- phase 1: load idx into registers + LDS histogram
    int ei[8], ej[8];
    #pragma unroll
    for (int k = 0; k < 8; ++k) {
        const int e = be0 + k * BLK + threadIdx.x;
        ei[k] = -1; ej[k] = -1;
        if (e < be1) {
            ei[k] = idx_i[e];
            ej[k] = idx_j[e];
            atomicAdd(&hist[ei[k] / APB], 1);
            atomicAdd(&hist[ej[k] / APB], 1);
        }
    }
    __syncthreads();   // <<< FIX (r11 bug): histogram must COMPLETE before copy
    for (int t = threadIdx.x; t < MAXB; t += blockDim.x) scan[t] = hist[t];
    __syncthreads();

    // ---- inclusive Hillis-Steele scan over MAXB=512 (2 slots/thread)
    for (int off = 1; off < MAXB; off <<= 1) {
        const int a = threadIdx.x, b2 = threadIdx.x + BLK;
        const int v0 = (a  >= off) ? scan[a  - off] : 0;
        const int v1 = (b2 >= off) ? scan[b2 - off] : 0;
        __syncthreads();
        scan[a]  += v0;
        scan[b2] += v1;
        __syncthreads();
    }

    // ---- reservation: one global atomic per non-empty bucket
    for (int t = threadIdx.x; t < B; t += blockDim.x) {
        const int h    = hist[t];
        const int excl = scan[t] - h;
        const int g    = h ? atomicAdd(&cnt[t], h) : 0;
        cur[t]    = excl;                 // staging cursor
        shiftb[t] = t * CAP + g - excl;   // rec idx = stg idx + shift
    }
    __syncthreads();

    // ---- phase 2: float loads, stress accum, stage records bucket-major
    #pragma unroll
    for (int k = 0; k < 8; ++k) {
        const int e = be0 + k * BLK + threadIdx.x;
        if (e >= be1) continue;
        const int i = ei[k], j = ej[k];
        const float dx = dEdRij[3*e+0], dy = dEdRij[3*e+1], dz = dEdRij[3*e+2];
        const float rx = Rij[3*e+0],    ry = Rij[3*e+1],    rz = Rij[3*e+2];

        const int m = idx_m[i];
        float* s = &smem[m * 9];
        atomicAdd(&s[0], rx * dx);
        atomicAdd(&s[1], rx * dy);
        atomicAdd(&s[2], rx * dz);
        atomicAdd(&s[3], ry * dx);
        atomicAdd(&s[4], ry * dy);
        atomicAdd(&s[5], ry * dz);
        atomicAdd(&s[6], rz * dx);
        atomicAdd(&s[7], rz * dy);
        atomicAdd(&s[8], rz * dz);

        int p = atomicAdd(&cur[i / APB], 1);
        stg[p] = make_float4(__int_as_float(i), dx, dy, dz);
        p = atomicAdd(&cur[j / APB], 1);
        stg[p] = make_float4(__int_as_float(j), -dx, -dy, -dz);
    }
    __syncthreads();

    // ---- stream-out: consecutive staging slots of a bucket -> consecutive
    //      rec slots => coalesced runs per bucket
    const int total = 2 * (be1 - be0);
    for (int t = threadIdx.x; t < total; t += blockDim.x) {
        const float4 q = stg[t];
        const int a = __float_as_int(q.x);
        const int b = a / APB;
        const int gidx = t + shiftb[b];
        if (gidx < (b + 1) * CAP)         // capacity guard (drop-only)
            rec[gidx] = q;
    }

    __syncthreads();
    float* sp = spart + (size_t)blockIdx.x * STRESS_FLOATS;
    for (int t = threadIdx.x; t < STRESS_FLOATS; t += blockDim.x)
        sp[t] += smem[t];
}

// ---------------------------------------------------------------------------
// Pass D: one block per bucket; 4-way unrolled independent loads -> LDS
// accumulate -> non-atomic add into forces (exclusive atom ownership).
// ---------------------------------------------------------------------------
__global__ void __launch_bounds__(256)
accum_kernel(const float4* __restrict__ rec,
             const int*    __restrict__ cnt,
             float* __restrict__ forces,
             int CAP, int n3)
{
    __shared__ float facc[APB * 3];
    const int b = blockIdx.x;
    for (int t = threadIdx.x; t < APB * 3; t += blockDim.x) facc[t] = 0.f;
    __syncthreads();

    int n = cnt[b];
    if (n > CAP) n = CAP;
    const float4* rb = rec + (size_t)b * CAP;
    const int abase = b * APB;

#define ACC(q)                                             \
    {                                                      \
        const int l = __float_as_int((q).x) - abase;       \
        atomicAdd(&facc[l * 3 + 0], (q).y);                \
        atomicAdd(&facc[l * 3 + 1], (q).z);                \
        atomicAdd(&facc[l * 3 + 2], (q).w);                \
    }

    int r = threadIdx.x;
    for (; r + 3 * BLK < n; r += 4 * BLK) {
        const float4 q0 = rb[r];
        const float4 q1 = rb[r + BLK];
        const float4 q2 = rb[r + 2 * BLK];
        const float4 q3 = rb[r + 3 * BLK];
        ACC(q0); ACC(q1); ACC(q2); ACC(q3);
    }
    for (; r < n; r += BLK) {
        const float4 q = rb[r];
        ACC(q);
    }
#undef ACC

    __syncthreads();
    const int o = abase * 3;
    for (int t = threadIdx.x; t < APB * 3; t += blockDim.x) {
        const int a3 = o + t;
        if (a3 < n3) forces[a3] += facc[t];
    }
}

// ---------------------------------------------------------------------------
// stress partials [rows][1152] -> d_out [1152], divided by cell volume
// ---------------------------------------------------------------------------
__global__ void reduce_stress_kernel(const float* __restrict__ spart,
                                     const float* __restrict__ cell,
                                     float* __restrict__ out_stress,
                                     int rows)
{
    int t = blockIdx.x * blockDim.x + threadIdx.x;
    if (t >= STRESS_FLOATS) return;
    float acc = 0.f;
    #pragma unroll 8
    for (int b = 0; b < rows; ++b)
        acc += spart[(size_t)b * STRESS_FLOATS + t];
    const int m = t / 9;
    const float* c = &cell[m * 9];
    const float a0 = c[0], a1 = c[1], a2 = c[2];
    const float b0 = c[3], b1 = c[4], b2 = c[5];
    const float c0 = c[6], c1 = c[7], c2 = c[8];
    const float x0 = b1 * c2 - b2 * c1;
    const float x1 = b2 * c0 - b0 * c2;
    const float x2 = b0 * c1 - b1 * c0;
    const float vol = a0 * x0 + a1 * x1 + a2 * x2;
    out_stress[t] = acc / vol;
}

// ===========================================================================
// Fallback: round-6 measured f64 atomic path (known passing)
// ===========================================================================
__global__ void zero_f64_kernel(double* __restrict__ p, int n) {
    int i = blockIdx.x * blockDim.x + threadIdx.x;
    if (i < n) p[i] = 0.0;
}

__global__ void __launch_bounds__(256)
edge_kernel_f64(const float* __restrict__ dEdRij,
                const float* __restrict__ Rij,
                const int*   __restrict__ idx_i,
                const int*   __restrict__ idx_j,
                const int*   __restrict__ idx_m,
                double* __restrict__ facc,
                float*  __restrict__ spart,
                int E)
{
    __shared__ float smem[STRESS_FLOATS];
    for (int t = threadIdx.x; t < STRESS_FLOATS; t += blockDim.x) smem[t] = 0.f;
    __syncthreads();
    const int stride = gridDim.x * blockDim.x;
    for (int e = blockIdx.x * blockDim.x + threadIdx.x; e < E; e += stride) {
        const int i = idx_i[e], j = idx_j[e];
        const float dx = dEdRij[3*e+0], dy = dEdRij[3*e+1], dz = dEdRij[3*e+2];
        const float rx = Rij[3*e+0],    ry = Rij[3*e+1],    rz = Rij[3*e+2];
        double* fi = facc + 3 * (size_t)i;
        unsafeAtomicAdd(fi + 0, (double) dx);
        unsafeAtomicAdd(fi + 1, (double) dy);
        unsafeAtomicAdd(fi + 2, (double) dz);
        double* fj = facc + 3 * (size_t)j;
        unsafeAtomicAdd(fj + 0, (double)-dx);
        unsafeAtomicAdd(fj + 1, (double)-dy);
        unsafeAtomicAdd(fj + 2, (double)-dz);
        const int m = idx_m[i];
        float* s = &smem[m * 9];
        atomicAdd(&s[0], rx*dx); atomicAdd(&s[1], rx*dy); atomicAdd(&s[2], rx*dz);
        atomicAdd(&s[3], ry*dx); atomicAdd(&s[4], ry*dy); atomicAdd(&s[5], ry*dz);
        atomicAdd(&s[6], rz*dx); atomicAdd(&s[7], rz*dy); atomicAdd(&s[8], rz*dz);
    }
    __syncthreads();
    float* sp = spart + (size_t)blockIdx.x * STRESS_FLOATS;
    for (int t = threadIdx.x; t < STRESS_FLOATS; t += blockDim.x) sp[t] = smem[t];
}

__global__ void reduce_forces_f64_kernel(const double* __restrict__ facc,
                                         float* __restrict__ forces, int n3)
{
    int t = blockIdx.x * blockDim.x + threadIdx.x;
    if (t < n3) forces[t] = (float)facc[t];
}

__global__ void reduce_stress_rows_kernel(const float* __restrict__ spart,
                                          const float* __restrict__ cell,
                                          float* __restrict__ out_stress,
                                          int rows)
{
    int t = blockIdx.x * blockDim.x + threadIdx.x;
    if (t >= STRESS_FLOATS) return;
    float acc = 0.f;
    for (int b = 0; b < rows; ++b)
        acc += spart[(size_t)b * STRESS_FLOATS + t];
    const int m = t / 9;
    const float* c = &cell[m * 9];
    const float a0 = c[0], a1 = c[1], a2 = c[2];
    const float b0 = c[3], b1 = c[4], b2 = c[5];
    const float c0 = c[6], c1 = c[7], c2 = c[8];
    const float x0 = b1*c2 - b2*c1, x1 = b2*c0 - b0*c2, x2 = b0*c1 - b1*c0;
    const float vol = a0*x0 + a1*x1 + a2*x2;
    out_stress[t] = acc / vol;
}

// ===========================================================================
extern "C" void kernel_launch(void* const* d_in, const int* in_sizes, int n_in,
                              void* d_out, int out_size, void* d_ws, size_t ws_size,
                              hipStream_t stream)
{
    const float* dEdRij = (const float*)d_in[0];
    const float* Rij    = (const float*)d_in[1];
    const float* R      = (const float*)d_in[2];  (void)R;
    const float* cell   = (const float*)d_in[3];
    const int*   idx_i  = (const int*)d_in[4];
    const int*   idx_j  = (const int*)d_in[5];
    const int*   idx_m  = (const int*)d_in[6];

    const int E  = in_sizes[0] / 3;   // 10,000,000
    const int N  = in_sizes[2] / 3;   // 200,000
    const int n3 = N * 3;

    float* out        = (float*)d_out;
    float* forces     = out;
    float* stress_out = out + (size_t)n3;

    const int B = (N + APB - 1) / APB;   // 500

    // ---- choose fewest chunks that fit:
    //      rec[B][CAP] + spart[rows][1152] + cnt[nchunks][B]
    int nchunks = 0, CAP = 0, ROWS = 0;
    size_t rec_f4 = 0, spart_f = 0;
    if (B <= MAXB) {
        const int cand[10] = {3, 4, 5, 8, 10, 12, 15, 20, 25, 40};
        for (int ci = 0; ci < 10; ++ci) {
            int nc   = cand[ci];
            int CH   = (E + nc - 1) / nc;
            int cap  = (3 * CH) / B + 64;        // 1.5x mean headroom
            int rows = (CH + EPB - 1) / EPB;
            size_t need = (size_t)B * cap * sizeof(float4)
                        + (size_t)rows * STRESS_FLOATS * sizeof(float)
                        + (size_t)nc * B * sizeof(int) + 256;
            if (need <= ws_size) {
                nchunks = nc; CAP = cap; ROWS = rows;
                rec_f4  = (size_t)B * cap;
                spart_f = (size_t)rows * STRESS_FLOATS;
                break;
            }
        }
    }

    if (nchunks > 0) {
        float4* rec   = (float4*)d_ws;
        float*  spart = (float*)(rec + rec_f4);
        int*    cnt   = (int*)(spart + spart_f);   // [nchunks][B]

        // zero spart + all cnt slices in one launch (contiguous 4B words)
        const size_t zf = spart_f + (size_t)nchunks * B;
        zero_f32_kernel<<<(int)((zf + BLK - 1) / BLK), BLK, 0, stream>>>(
            spart, zf);
        zero_f32_kernel<<<(n3 + BLK - 1) / BLK, BLK, 0, stream>>>(
            forces, (size_t)n3);

        const int CH = (E + nchunks - 1) / nchunks;
        int chunk = 0;
        for (int s = 0; s < E; s += CH, ++chunk) {
            const int ce = min(CH, E - s);
            const int nb = (ce + EPB - 1) / EPB;

            scatter_kernel<<<nb, BLK, 0, stream>>>(
                dEdRij, Rij, idx_i, idx_j, idx_m,
                rec, cnt + (size_t)chunk * B, spart, s, ce, B, CAP);

            accum_kernel<<<B, BLK, 0, stream>>>(
                rec, cnt + (size_t)chunk * B, forces, CAP, n3);
        }

        reduce_stress_kernel<<<(STRESS_FLOATS + BLK - 1) / BLK, BLK, 0, stream>>>(
            spart, cell, stress_out, ROWS);
    } else {
        // fallback: measured f64 atomic path
        double* facc   = (double*)d_ws;
        float*  spartf = (float*)(facc + n3);

        zero_f64_kernel<<<(n3 + BLK - 1) / BLK, BLK, 0, stream>>>(facc, n3);
        edge_kernel_f64<<<2048, BLK, 0, stream>>>(
            dEdRij, Rij, idx_i, idx_j, idx_m, facc, spartf, E);
        reduce_forces_f64_kernel<<<(n3 + BLK - 1) / BLK, BLK, 0, stream>>>(
            facc, forces, n3);
        reduce_stress_rows_kernel<<<(STRESS_FLOATS + BLK - 1) / BLK, BLK, 0, stream>>>(
            spartf, cell, stress_out, 2048);
    }
}